// Round 1
// baseline (29.373 us; speedup 1.0000x reference)
//
#include <hip/hip_runtime.h>

// Problem constants (fixed by setup_inputs)
constexpr int BSZ  = 32;          // batch
constexpr int LCH  = 256;         // channels
constexpr int SPA  = 256;         // 16*16 spatial
constexpr int NPAIR = BSZ * BSZ;  // 1024

// distances[i,j] = sum_{k >= bins(i,j)} w[k] * sum_s |x[j,k,s] - x[i,k,s]|
//   w[k]      = 2^((255-k)/20)          (mean-normalization cancels in the ratio)
//   bins(i,j) = clip(ceil(log2(|ts_j-ts_i|+1)*20), 0, 256)
// output = mean over all (i,j) pairs.

__global__ __launch_bounds__(256) void ts_pair_kernel(
    const float* __restrict__ latents,
    const int*   __restrict__ ts,
    float*       __restrict__ partial)
{
    const int pair = blockIdx.x;      // 0..1023
    const int i = pair >> 5;
    const int j = pair & 31;
    const int t = threadIdx.x;        // 0..255

    __shared__ float weff[LCH];

    // bins for this pair (cheap; every thread computes it identically)
    const float dt = fabsf((float)(ts[j] - ts[i])) + 1.0f;
    int bins = (int)ceilf(log2f(dt) * 20.0f);
    bins = min(max(bins, 0), LCH);

    // effective per-channel weight: 0 below bins, 2^((255-k)/20) at/above
    weff[t] = (t >= bins) ? exp2f((float)(LCH - 1 - t) * (1.0f / 20.0f)) : 0.0f;
    __syncthreads();

    const float4* __restrict__ xi =
        reinterpret_cast<const float4*>(latents + (size_t)i * (LCH * SPA));
    const float4* __restrict__ xj =
        reinterpret_cast<const float4*>(latents + (size_t)j * (LCH * SPA));

    // 65536 floats = 16384 float4 per image; 256 threads -> 64 float4 each.
    // float4 index f4 = it*256 + t  -> channel k = f4>>6 = it*4 + (t>>6)
    // (wave-uniform -> LDS broadcast read of weff)
    float acc = 0.0f;
#pragma unroll 8
    for (int it = 0; it < 64; ++it) {
        const int f4 = (it << 8) + t;
        const float w = weff[(it << 2) + (t >> 6)];
        const float4 a = xi[f4];
        const float4 b = xj[f4];
        const float d = fabsf(a.x - b.x) + fabsf(a.y - b.y) +
                        fabsf(a.z - b.z) + fabsf(a.w - b.w);
        acc = fmaf(w, d, acc);
    }

    // block reduce: wave64 shuffle tree, then 4 wave sums via LDS
    for (int off = 32; off > 0; off >>= 1)
        acc += __shfl_down(acc, off, 64);
    __shared__ float wsum[4];
    if ((t & 63) == 0) wsum[t >> 6] = acc;
    __syncthreads();
    if (t == 0) partial[pair] = wsum[0] + wsum[1] + wsum[2] + wsum[3];
}

__global__ __launch_bounds__(256) void ts_reduce_kernel(
    const float* __restrict__ partial,
    float*       __restrict__ out)
{
    const int t = threadIdx.x;
    // deterministic final reduction in double (no atomics)
    double s = (double)partial[t] + (double)partial[t + 256] +
               (double)partial[t + 512] + (double)partial[t + 768];
    for (int off = 32; off > 0; off >>= 1)
        s += __shfl_down(s, off, 64);
    __shared__ double ds[4];
    if ((t & 63) == 0) ds[t >> 6] = s;
    __syncthreads();
    if (t == 0) out[0] = (float)((ds[0] + ds[1] + ds[2] + ds[3]) * (1.0 / NPAIR));
}

extern "C" void kernel_launch(void* const* d_in, const int* in_sizes, int n_in,
                              void* d_out, int out_size, void* d_ws, size_t ws_size,
                              hipStream_t stream)
{
    const float* latents = (const float*)d_in[0];
    const int*   ts      = (const int*)d_in[1];
    float*       out     = (float*)d_out;
    float*       partial = (float*)d_ws;   // 1024 floats of scratch

    ts_pair_kernel<<<NPAIR, 256, 0, stream>>>(latents, ts, partial);
    ts_reduce_kernel<<<1, 256, 0, stream>>>(partial, out);
}

// Round 2
// 13.606 us; speedup vs baseline: 2.1588x; 2.1588x over previous
//
#include <hip/hip_runtime.h>

// Problem constants (fixed by setup_inputs)
constexpr int BSZ  = 32;          // batch
constexpr int LCH  = 256;         // channels
constexpr int SPA  = 256;         // 16*16 spatial
constexpr int NPAIRS = (BSZ * (BSZ - 1)) / 2;   // 496 unordered pairs

// total = 2 * sum_{i<j} sum_{k >= bins(i,j)} w[k] * sum_s |x[j,k,s]-x[i,k,s]|
//   w[k]      = 2^((255-k)/20)   (mean-normalization cancels in the ratio)
//   bins(i,j) = clip(ceil(log2(|ts_j-ts_i|+1)*20), 0, 256);  diagonal -> 0
// out = total / 1024

// pair linearization (i<j): p = 30*i - i*(i-1)/2 + j - 1
__device__ __forceinline__ constexpr int pair_idx(int i, int j) {
    return 30 * i - (i * (i - 1)) / 2 + j - 1;
}

template <int PLO, int PHI>
__device__ __forceinline__ void accum_pairs(const float2 x[BSZ], const float* gs,
                                            float& ax, float& ay) {
#pragma unroll
    for (int i = 0; i < BSZ - 1; ++i) {
#pragma unroll
        for (int j = i + 1; j < BSZ; ++j) {
            const int p = pair_idx(i, j);
            if (p >= PLO && p < PHI) {   // compile-time pruned after unroll
                const float g = gs[p];   // ds_read_b32, constant offset, broadcast
                ax = fmaf(g, fabsf(x[i].x - x[j].x), ax);
                ay = fmaf(g, fabsf(x[i].y - x[j].y), ay);
            }
        }
    }
}

__global__ __launch_bounds__(256) void ts_site_kernel(
    const float* __restrict__ latents,
    const int*   __restrict__ ts,
    float*       __restrict__ partial)
{
    const int k    = blockIdx.x;       // channel 0..255
    const int tid  = threadIdx.x;      // 0..255
    const int posT = tid & 127;        // float2 position 0..127 (covers 256 spatial)
    const int grp  = tid >> 7;         // pair-group 0 or 1 (wave-uniform)

    __shared__ float gs[NPAIRS];       // per-pair gate for this channel

    // gates: g[p] = (bins(i,j) <= k) ? 1 : 0
    for (int p = tid; p < NPAIRS; p += 256) {
        int i = 0;
        while (31 * (i + 1) - ((i + 1) * i) / 2 <= p) ++i;   // start(i+1) <= p
        const int j = p - 30 * i + (i * (i - 1)) / 2 + 1;
        const float dt = fabsf((float)(ts[j] - ts[i])) + 1.0f;
        int b = (int)ceilf(log2f(dt) * 20.0f);
        b = min(max(b, 0), LCH);
        gs[p] = (b <= k) ? 1.0f : 0.0f;
    }
    __syncthreads();

    // load all 32 batch values for this (k, 2 spatial positions) into registers
    const float2* __restrict__ xf2 = reinterpret_cast<const float2*>(latents);
    float2 x[BSZ];
#pragma unroll
    for (int b = 0; b < BSZ; ++b)
        x[b] = xf2[((size_t)b << 15) + ((size_t)k << 7) + posT];

    float ax = 0.0f, ay = 0.0f;
    if (grp == 0) accum_pairs<0, 248>(x, gs, ax, ay);
    else          accum_pairs<248, NPAIRS>(x, gs, ax, ay);

    // block reduce (unweighted), then apply w[k] once
    float acc = ax + ay;
    for (int off = 32; off > 0; off >>= 1)
        acc += __shfl_down(acc, off, 64);
    __shared__ float wsum[4];
    if ((tid & 63) == 0) wsum[tid >> 6] = acc;
    __syncthreads();
    if (tid == 0) {
        const float wk = exp2f((float)(LCH - 1 - k) * (1.0f / 20.0f));
        partial[k] = (wsum[0] + wsum[1] + wsum[2] + wsum[3]) * wk;
    }
}

__global__ __launch_bounds__(64) void ts_reduce_kernel(
    const float* __restrict__ partial,
    float*       __restrict__ out)
{
    const int t = threadIdx.x;   // 0..63
    double s = 0.0;
#pragma unroll
    for (int r = 0; r < 4; ++r) s += (double)partial[t + 64 * r];
    for (int off = 32; off > 0; off >>= 1)
        s += __shfl_down(s, off, 64);
    if (t == 0) out[0] = (float)(s * (2.0 / 1024.0));   // symmetry x2, mean /1024
}

extern "C" void kernel_launch(void* const* d_in, const int* in_sizes, int n_in,
                              void* d_out, int out_size, void* d_ws, size_t ws_size,
                              hipStream_t stream)
{
    const float* latents = (const float*)d_in[0];
    const int*   ts      = (const int*)d_in[1];
    float*       out     = (float*)d_out;
    float*       partial = (float*)d_ws;   // 256 floats of scratch

    ts_site_kernel<<<LCH, 256, 0, stream>>>(latents, ts, partial);
    ts_reduce_kernel<<<1, 64, 0, stream>>>(partial, out);
}